// Round 8
// baseline (438.202 us; speedup 1.0000x reference)
//
#include <hip/hip_runtime.h>
#include <hip/hip_bf16.h>

// PLRNN step: out = A*z + relu(z - rowmean(z)) @ W^T + h,  A=diag(AW), W=AW-diag
// Rewritten: out = (z_act @ AW^T) + [A*min(z,mu) + h]   (exact identity)
// Round 11: producer/consumer wave specialization. Evidence: r9 (ILP +4%),
// r10 (occupancy 41->78%, dur unchanged) -> not latency-bound within phases;
// MfmaUtil 13% says the K-loop is ~1/3 of the timeline -> the three phases
// (HBM-read, L2-bound GEMM, HBM-write) SERIALIZE per CU and the 2 resident
// blocks stay phase-locked. Fix: 1 persistent block/CU, waves 0-7 produce
// tile j (z->mean->relu/corr->sA/sC) while waves 8-15 consume tile j-1
// (K-loop from L2 + epilogue stores) via double-buffered LDS. All three
// resource streams run concurrently. Unlike r8: wave-level stream separation
// (no per-wave load/store interleave -> no partial-line poison) and
// consecutive tiles per block (contiguous 512KB z/out region per CU).
// Barriers are raw lgkmcnt(0)+s_barrier: no vmcnt drain, so B prefetches
// and stores stay in flight across the barrier (T4).

#define DZV 512
#define BM 32
#define LDA 520   // LDS row stride (shorts): 1040 B, 16B-aligned, non-pow2 bank stride
#define TPB 8     // consecutive tiles per block
#define NBLK 256  // 2048 tiles / TPB

typedef __attribute__((ext_vector_type(8))) short short8;  // 8 bf16 = 4 VGPRs
typedef __attribute__((ext_vector_type(4))) float f32x4;   // MFMA C/D frag

__device__ __forceinline__ unsigned short f2bf(float x) {
  __hip_bfloat16 b = __float2bfloat16(x);
  return __builtin_bit_cast(unsigned short, b);
}
__device__ __forceinline__ float bf2f(unsigned short u) {
  return __builtin_bit_cast(float, (unsigned int)u << 16);
}

// Prep: pack AW (fp32) into bf16 MFMA-B-fragment order + extract diagonal.
// Frag idx=(T*16+s)*64+L holds 8 bf16 = AW[T*16+(L&15)][s*32+(L>>4)*8 + j]:
// a wave's B-frag load (lane L reads idx base+L) is 1KB contiguous, L2-hot.
__global__ void pack_b(const float* __restrict__ AW, unsigned short* __restrict__ AWp,
                       float* __restrict__ Adiag) {
  int idx = blockIdx.x * 256 + threadIdx.x;     // 0..32767
  int L = idx & 63, s = (idx >> 6) & 15, T = idx >> 10;
  int n = T * 16 + (L & 15);
  int k = s * 32 + (L >> 4) * 8;
  const float4* src = (const float4*)(AW + n * DZV + k);
  float4 a = src[0], b = src[1];
  union { unsigned short u[8]; short8 v; } p;
  p.u[0] = f2bf(a.x); p.u[1] = f2bf(a.y); p.u[2] = f2bf(a.z); p.u[3] = f2bf(a.w);
  p.u[4] = f2bf(b.x); p.u[5] = f2bf(b.y); p.u[6] = f2bf(b.z); p.u[7] = f2bf(b.w);
  *(short8*)(AWp + idx * 8) = p.v;
  if (idx < DZV) Adiag[idx] = AW[idx * (DZV + 1)];
}

__global__ __launch_bounds__(1024, 4) void plrnn_step(
    const float* __restrict__ z, const float* __restrict__ h,
    const unsigned short* __restrict__ AWp, const float* __restrict__ Adiag,
    float* __restrict__ out)
{
  __shared__ unsigned short sA[2][BM * LDA];  // z_act panels (bf16), 2x33.3 KB
  __shared__ unsigned short sC[2][BM * LDA];  // corr panels (bf16), 2x33.3 KB

  const int t = threadIdx.x;
  const int lane = t & 63;
  const int wave = t >> 6;            // 0..15
  const bool prod = wave < 8;         // wave-uniform role split
  const long tile0 = (long)blockIdx.x * TPB;

  // ---- consumer setup (waves 8-15): 64 output cols each ----
  const int cw = wave & 7;
  const int lr = lane & 15;
  const int quad = lane >> 4;
  const int nbase = cw * 64;
  const unsigned short* bb[4];
  #pragma unroll
  for (int nt = 0; nt < 4; ++nt)
    bb[nt] = AWp + (((cw * 4 + nt) * 16) * 64 + lane) * 8;

  // B frag double-buffer; wrap-prefetch (s+1)&15 keeps it warm across tiles.
  short8 bf[2][4];
  if (!prod) {
    #pragma unroll
    for (int nt = 0; nt < 4; ++nt)
      bf[0][nt] = *(const short8*)(bb[nt]);   // s=0, once
  }

  // ---- producer setup (waves 0-7): 4 rows each, 16 lanes per row ----
  const int prow = (wave & 7) * 4 + (lane >> 4);  // 0..31
  const int pc = lane & 15;

  for (int j = 0; j <= TPB; ++j) {
    if (prod) {
      if (j < TPB) {                  // produce tile j into buf j&1
        const int buf = j & 1;
        const float4* zr = (const float4*)(z + ((tile0 + j) * BM + prow) * (long)DZV);
        float4 v[8];
        float s = 0.f;
        #pragma unroll
        for (int i = 0; i < 8; ++i) {
          v[i] = zr[pc + i * 16];               // coalesced 256B runs (HBM/L3)
          s += (v[i].x + v[i].y) + (v[i].z + v[i].w);
        }
        s += __shfl_xor(s, 1);
        s += __shfl_xor(s, 2);
        s += __shfl_xor(s, 4);
        s += __shfl_xor(s, 8);
        const float mu = s * (1.0f / 512.0f);
        #pragma unroll
        for (int i = 0; i < 8; ++i) {
          const int c4 = pc + i * 16;           // float4 column index
          float4 Ad = ((const float4*)Adiag)[c4];   // L1-hot, 2KB shared
          float4 hv = ((const float4*)h)[c4];
          union { unsigned short u[4]; ushort4 v4; } pa, pk;
          pa.u[0] = f2bf(fmaxf(v[i].x - mu, 0.f));
          pa.u[1] = f2bf(fmaxf(v[i].y - mu, 0.f));
          pa.u[2] = f2bf(fmaxf(v[i].z - mu, 0.f));
          pa.u[3] = f2bf(fmaxf(v[i].w - mu, 0.f));
          pk.u[0] = f2bf(Ad.x * fminf(v[i].x, mu) + hv.x);
          pk.u[1] = f2bf(Ad.y * fminf(v[i].y, mu) + hv.y);
          pk.u[2] = f2bf(Ad.z * fminf(v[i].z, mu) + hv.z);
          pk.u[3] = f2bf(Ad.w * fminf(v[i].w, mu) + hv.w);
          *(ushort4*)&sA[buf][prow * LDA + c4 * 4] = pa.v4;
          *(ushort4*)&sC[buf][prow * LDA + c4 * 4] = pk.v4;
        }
      }
    } else {
      if (j >= 1) {                   // consume tile j-1 from buf (j-1)&1
        const int buf = (j - 1) & 1;
        const long row0 = (tile0 + (j - 1)) * BM;
        const unsigned short* a0 = &sA[buf][lr * LDA + quad * 8];
        const unsigned short* a1 = a0 + 16 * LDA;
        short8 af[2][2];
        af[0][0] = *(const short8*)(a0);
        af[0][1] = *(const short8*)(a1);
        f32x4 acc[2][4];
        #pragma unroll
        for (int mt = 0; mt < 2; ++mt)
          #pragma unroll
          for (int nt = 0; nt < 4; ++nt)
            acc[mt][nt] = (f32x4){0.f, 0.f, 0.f, 0.f};

        #pragma unroll
        for (int s = 0; s < 16; ++s) {          // k = s*32
          const int cur = s & 1, nxt = cur ^ 1;
          #pragma unroll
          for (int nt = 0; nt < 4; ++nt)        // wrap-prefetch: (s+1)&15
            bf[nxt][nt] = *(const short8*)(bb[nt] + ((s + 1) & 15) * 512);
          if (s < 15) {                         // A prefetch (ds_read_b128)
            af[nxt][0] = *(const short8*)(a0 + (s + 1) * 32);
            af[nxt][1] = *(const short8*)(a1 + (s + 1) * 32);
          }
          #pragma unroll
          for (int nt = 0; nt < 4; ++nt) {
            acc[0][nt] = __builtin_amdgcn_mfma_f32_16x16x32_bf16(af[cur][0], bf[cur][nt], acc[0][nt], 0, 0, 0);
            acc[1][nt] = __builtin_amdgcn_mfma_f32_16x16x32_bf16(af[cur][1], bf[cur][nt], acc[1][nt], 0, 0, 0);
          }
        }

        // epilogue: out = acc + corr; nt innermost -> 4 adjacent 64B segments
        // per row back-to-back so L2 merges full lines (r3-proven pattern).
        #pragma unroll
        for (int mt = 0; mt < 2; ++mt) {
          #pragma unroll
          for (int r = 0; r < 4; ++r) {
            const int lm = mt * 16 + quad * 4 + r;   // C/D: row = quad*4 + reg
            float corr[4];
            #pragma unroll
            for (int nt = 0; nt < 4; ++nt)
              corr[nt] = bf2f(sC[buf][lm * LDA + nbase + nt * 16 + lr]);
            float* orow = out + (row0 + lm) * (long)DZV + nbase + lr;
            #pragma unroll
            for (int nt = 0; nt < 4; ++nt)
              orow[nt * 16] = acc[mt][nt][r] + corr[nt];
          }
        }
      }
    }
    // Raw barrier: order LDS (lgkmcnt) only; B prefetches and out-stores
    // (vmcnt) deliberately stay in flight across it. "memory" clobber pins
    // all memory ops on their side of the barrier.
    asm volatile("s_waitcnt lgkmcnt(0)\n\ts_barrier" ::: "memory");
  }
}

extern "C" void kernel_launch(void* const* d_in, const int* in_sizes, int n_in,
                              void* d_out, int out_size, void* d_ws, size_t ws_size,
                              hipStream_t stream) {
  const float* z  = (const float*)d_in[0];
  const float* AW = (const float*)d_in[1];
  const float* h  = (const float*)d_in[2];
  float* out = (float*)d_out;
  unsigned short* AWp = (unsigned short*)d_ws;                     // 512 KB packed bf16
  float* Adiag = (float*)((char*)d_ws + DZV * DZV * sizeof(unsigned short)); // 2 KB

  pack_b<<<128, 256, 0, stream>>>(AW, AWp, Adiag);
  plrnn_step<<<NBLK, 1024, 0, stream>>>(z, h, AWp, Adiag, out);
}